// Round 17
// baseline (127.363 us; speedup 1.0000x reference)
//
#include <hip/hip_runtime.h>
#include <stdint.h>

// Problem constants
#define BB 2
#define TT 2048
#define CC 1024
#define NH 16
#define HD 64
#define NG 32              // groups per C row (group size 32)
#define ROWS (BB*TT)       // 4096
#define C3 (3*CC)          // 3072

typedef _Float16 half_t;
typedef __attribute__((ext_vector_type(8))) _Float16 half8;
typedef __attribute__((ext_vector_type(2))) __fp16 fp16x2;
typedef __attribute__((ext_vector_type(4))) float f32x4;

#define GLDS16(g, l) __builtin_amdgcn_global_load_lds( \
    (__attribute__((address_space(1))) void*)(g), \
    (__attribute__((address_space(3))) void*)(l), 16, 0, 0)

#define LOG2E 1.44269504f
#define DEFER_THR 5.5451774f   /* 8 / log2(e) */

__device__ __forceinline__ uint32_t pk_h2(float a, float b) {
  union { fp16x2 h; uint32_t u; } cv;
  cv.h = __builtin_amdgcn_cvt_pkrtz(a, b);
  return cv.u;
}

// ---------------------------------------------------------------------------
// merged pre-pass (r16, passing): blocks [0,512) weight qdq; [512,1024) LN qdq
// ---------------------------------------------------------------------------
__global__ void k_pre(const float* __restrict__ w1, const float* __restrict__ w2,
                      half_t* __restrict__ o1, half_t* __restrict__ o2,
                      const int* __restrict__ qx, const float* __restrict__ sx,
                      const float* __restrict__ mean, const float* __restrict__ rstd,
                      const float* __restrict__ lnw, half_t* __restrict__ h16) {
  const int blk = blockIdx.x;
  if (blk < 512) {
    int g = blk * blockDim.x + threadIdx.x;
    const float* src; half_t* dst; int gl;
    if (g < C3 * NG) { src = w1; dst = o1; gl = g; }
    else             { src = w2; dst = o2; gl = g - C3 * NG; }
    const float4* p = reinterpret_cast<const float4*>(src + (size_t)gl * 32);
    float v[32]; float amax = 0.f;
    #pragma unroll
    for (int i = 0; i < 8; ++i) {
      float4 t = p[i];
      v[4*i] = t.x; v[4*i+1] = t.y; v[4*i+2] = t.z; v[4*i+3] = t.w;
      amax = fmaxf(amax, fmaxf(fmaxf(fabsf(t.x), fabsf(t.y)), fmaxf(fabsf(t.z), fabsf(t.w))));
    }
    float s = fmaxf(amax / 127.0f, 1e-8f);
    half_t* o = dst + (size_t)gl * 32;
    #pragma unroll
    for (int c = 0; c < 4; ++c) {
      half8 ov;
      #pragma unroll
      for (int jj = 0; jj < 8; ++jj) {
        float q = fminf(fmaxf(rintf(v[c*8+jj] / s), -127.f), 127.f);
        ov[jj] = (half_t)(q * s);
      }
      *reinterpret_cast<half8*>(o + c*8) = ov;
    }
  } else {
    int g = (blk - 512) * blockDim.x + threadIdx.x;
    int row = g >> 5, grp = g & 31;
    float sxv = sx[g];
    float mu = mean[row], rs = rstd[row];
    const int4* qp = reinterpret_cast<const int4*>(qx + (size_t)row * CC + grp * 32);
    const float4* wp = reinterpret_cast<const float4*>(lnw + grp * 32);
    float v[32]; float amax = 0.f;
    #pragma unroll
    for (int i = 0; i < 8; ++i) {
      int4 qv = qp[i]; float4 wv = wp[i];
      float h0 = ((float)qv.x * sxv - mu) * rs * wv.x;
      float h1 = ((float)qv.y * sxv - mu) * rs * wv.y;
      float h2 = ((float)qv.z * sxv - mu) * rs * wv.z;
      float h3 = ((float)qv.w * sxv - mu) * rs * wv.w;
      v[4*i] = h0; v[4*i+1] = h1; v[4*i+2] = h2; v[4*i+3] = h3;
      amax = fmaxf(amax, fmaxf(fmaxf(fabsf(h0), fabsf(h1)), fmaxf(fabsf(h2), fabsf(h3))));
    }
    float s = fmaxf(amax / 127.0f, 1e-8f);
    half_t* o = h16 + (size_t)row * CC + grp * 32;
    #pragma unroll
    for (int c = 0; c < 4; ++c) {
      half8 ov;
      #pragma unroll
      for (int jj = 0; jj < 8; ++jj) {
        float q = fminf(fmaxf(rintf(v[c*8+jj] / s), -127.f), 127.f);
        ov[jj] = (half_t)(q * s);
      }
      *reinterpret_cast<half8*>(o + c*8) = ov;
    }
  }
}

// ---------------------------------------------------------------------------
// 8-phase 256x256 GEMM (m198-style: linear LDS, counted vmcnt, raw barriers).
// Out[m][n] = sum_k A[m][k]*B[n][k], M=4096 N=3072 K=1024, fp16 out.
// 512 thr / 8 waves (2M x 4N); wave owns 128x64 C (8x4 16x16 frags).
// LDS 128KB: A[2buf][256][64] + B[2buf][256][64]; buf0=even K-tiles, buf1=odd.
// Cycle e (8 phases) computes tiles 2e (p0-3) and 2e+1 (p4-7), one C-quadrant
// + K=64 per phase (16 MFMA). Stage slots (1 half-tile = 2 GLDS16 per phase):
//   p0,p1: A-odd <- tile 2e+1 | p2,p3: B-even <- 2e+2 | p4,p5: A-even <- 2e+2
//   p6,p7: B-odd <- 2e+3.  vmcnt(4) at end-p3/p7 (vmcnt(0) last cycle's p3)
// completes exactly the slots the next quadrant reads (derivation in notes).
// ---------------------------------------------------------------------------
__global__ __launch_bounds__(512, 2) void k_gemm8p(const half_t* __restrict__ A,
                                                   const half_t* __restrict__ B,
                                                   half_t* __restrict__ Out) {
  __shared__ __align__(16) half_t lds[65536];   // 128 KB
  const int tid = threadIdx.x;
  const int wave = tid >> 6, lane = tid & 63;
  const int l15 = lane & 15, lg = lane >> 4;
  const int flat = blockIdx.y * 12 + blockIdx.x;        // 192 blocks, %8==0
  const int swz = (flat & 7) * 24 + (flat >> 3);        // XCD-bijective
  const int m0 = (swz / 12) * 256, n0 = (swz % 12) * 256;
  const int wmg = (wave >> 2) * 128;                    // A row half (0/128)
  const int wn  = (wave & 3) * 64;                      // B col group
  const int srow = wave * 8 + (lane >> 3);              // staging row in 64-blk
  const int scol = (lane & 7) * 8;                      // staging col (halves)

  f32x4 acc[8][4];
  #pragma unroll
  for (int i = 0; i < 8; ++i)
    #pragma unroll
    for (int jj = 0; jj < 4; ++jj) acc[i][jj] = f32x4{0.f, 0.f, 0.f, 0.f};
  half8 breg[4][2];

  auto stageA = [&](int buf, int hf, int T) {
    #pragma unroll
    for (int i = 0; i < 2; ++i)
      GLDS16(A + (size_t)(m0 + hf*128 + i*64 + srow) * 1024 + T*64 + scol,
             lds + buf*16384 + hf*8192 + i*4096 + wave*512);
  };
  auto stageB = [&](int buf, int hf, int T) {
    #pragma unroll
    for (int i = 0; i < 2; ++i)
      GLDS16(B + (size_t)(n0 + hf*128 + i*64 + srow) * 1024 + T*64 + scol,
             lds + 32768 + buf*16384 + hf*8192 + i*4096 + wave*512);
  };

  // prologue: tile0 fully + tile1's B; drain; barrier.
  stageB(0, 0, 0); stageB(0, 1, 0); stageA(0, 0, 0); stageA(0, 1, 0);
  stageB(1, 0, 1); stageB(1, 1, 1);
  asm volatile("s_waitcnt vmcnt(0)" ::: "memory");
  __builtin_amdgcn_s_barrier();

  for (int e = 0; e < 8; ++e) {
    #pragma unroll
    for (int p = 0; p < 8; ++p) {
      const int tau = p >> 2, q = p & 3;
      // ---- ds-loads for this phase ----
      if (q == 0) {
        #pragma unroll
        for (int nj = 0; nj < 4; ++nj)
          #pragma unroll
          for (int ks = 0; ks < 2; ++ks)
            breg[nj][ks] = *reinterpret_cast<const half8*>(
                lds + 32768 + tau*16384 + (wn + nj*16 + l15)*64 + ks*32 + lg*8);
      }
      half8 a[2][2];
      #pragma unroll
      for (int mi = 0; mi < 2; ++mi)
        #pragma unroll
        for (int ks = 0; ks < 2; ++ks)
          a[mi][ks] = *reinterpret_cast<const half8*>(
              lds + tau*16384 + (wmg + q*32 + mi*16 + l15)*64 + ks*32 + lg*8);
      // ---- stage this phase's half-tile ----
      {
        int T;
        switch (p) {
          case 0: T = 2*e + 1; if (T < 16) stageA(1, 0, T); break;
          case 1: T = 2*e + 1; if (T < 16) stageA(1, 1, T); break;
          case 2: T = 2*e + 2; if (T < 16) stageB(0, 0, T); break;
          case 3: T = 2*e + 2; if (T < 16) stageB(0, 1, T); break;
          case 4: T = 2*e + 2; if (T < 16) stageA(0, 0, T); break;
          case 5: T = 2*e + 2; if (T < 16) stageA(0, 1, T); break;
          case 6: T = 2*e + 3; if (T < 16) stageB(1, 0, T); break;
          default: T = 2*e + 3; if (T < 16) stageB(1, 1, T); break;
        }
      }
      __builtin_amdgcn_s_barrier();
      asm volatile("s_waitcnt lgkmcnt(0)" ::: "memory");
      __builtin_amdgcn_sched_barrier(0);
      // ---- 16 MFMA: quadrant q of tile tau ----
      __builtin_amdgcn_s_setprio(1);
      #pragma unroll
      for (int ks = 0; ks < 2; ++ks)
        #pragma unroll
        for (int mi = 0; mi < 2; ++mi)
          #pragma unroll
          for (int nj = 0; nj < 4; ++nj)
            acc[q*2 + mi][nj] = __builtin_amdgcn_mfma_f32_16x16x32_f16(
                a[mi][ks], breg[nj][ks], acc[q*2 + mi][nj], 0, 0, 0);
      __builtin_amdgcn_s_setprio(0);
      if (p == 3) {
        if (e == 7) { asm volatile("s_waitcnt vmcnt(0)" ::: "memory"); }
        else        { asm volatile("s_waitcnt vmcnt(4)" ::: "memory"); }
      } else if (p == 7 && e != 7) {
        asm volatile("s_waitcnt vmcnt(4)" ::: "memory");
      }
      __builtin_amdgcn_s_barrier();
    }
  }

  // epilogue: scatter fp16 stores (same per-element pattern as r11 GEMM)
  const int crow = m0 + wmg + lg * 4;
  const int ccol = n0 + wn + l15;
  #pragma unroll
  for (int mi = 0; mi < 8; ++mi)
    #pragma unroll
    for (int nj = 0; nj < 4; ++nj)
      #pragma unroll
      for (int r = 0; r < 4; ++r)
        Out[(size_t)(crow + mi*16 + r) * C3 + ccol + nj*16] = (half_t)acc[mi][nj][r];
}

// ---------------------------------------------------------------------------
// fp16 MFMA GEMM (r11, passing): 128x128 tile, BK=32 double-buffered,
// XCD-bijective swizzle, split-K via blockIdx.z.  (used for GEMM2)
// ---------------------------------------------------------------------------
template<typename TO>
__global__ __launch_bounds__(256) void k_gemm16(const half_t* __restrict__ A,
                                                const half_t* __restrict__ B,
                                                TO* __restrict__ Out, int N,
                                                int gx, int cpx, int klen) {
  __shared__ __align__(16) half_t As[2][128*32];
  __shared__ __align__(16) half_t Bs[2][128*32];
  const int tid = threadIdx.x;
  const int wave = tid >> 6, lane = tid & 63;
  const int l15 = lane & 15, lg = lane >> 4;
  const int flat = blockIdx.y * gx + blockIdx.x;
  const int swz = (flat & 7) * cpx + (flat >> 3);
  const int m0 = (swz / gx) * 128, n0 = (swz % gx) * 128;
  const int kbeg = blockIdx.z * klen;
  TO* out = Out + (size_t)blockIdx.z * ROWS * N;
  const int wm = (wave >> 1) * 64, wn = (wave & 1) * 64;
  f32x4 acc[4][4];
  #pragma unroll
  for (int i = 0; i < 4; ++i)
    #pragma unroll
    for (int jj = 0; jj < 4; ++jj) acc[i][jj] = f32x4{0.f, 0.f, 0.f, 0.f};
  const int srow = lane >> 2;
  const int scol = (lane & 3) * 8;
  const int seg0 = wave * 2;
  auto stage = [&](int buf, int k0) {
    #pragma unroll
    for (int s = 0; s < 2; ++s) {
      const int seg = seg0 + s;
      GLDS16(A + (size_t)(m0 + seg*16 + srow) * 1024 + k0 + scol, &As[buf][0] + seg*512);
      GLDS16(B + (size_t)(n0 + seg*16 + srow) * 1024 + k0 + scol, &Bs[buf][0] + seg*512);
    }
  };
  stage(0, kbeg);
  __syncthreads();
  int cur = 0;
  for (int k0 = kbeg; k0 < kbeg + klen; k0 += 32) {
    if (k0 + 32 < kbeg + klen) stage(cur ^ 1, k0 + 32);
    half8 af[4], bf[4];
    #pragma unroll
    for (int i = 0; i < 4; ++i) {
      af[i] = *reinterpret_cast<const half8*>(&As[cur][0] + (wm + i*16 + l15)*32 + lg*8);
      bf[i] = *reinterpret_cast<const half8*>(&Bs[cur][0] + (wn + i*16 + l15)*32 + lg*8);
    }
    #pragma unroll
    for (int mi = 0; mi < 4; ++mi)
      #pragma unroll
      for (int ni = 0; ni < 4; ++ni)
        acc[mi][ni] = __builtin_amdgcn_mfma_f32_16x16x32_f16(af[mi], bf[ni], acc[mi][ni], 0, 0, 0);
    __syncthreads();
    cur ^= 1;
  }
  const int crow = m0 + wm + lg * 4;
  const int ccol = n0 + wn + l15;
  #pragma unroll
  for (int mi = 0; mi < 4; ++mi)
    #pragma unroll
    for (int ni = 0; ni < 4; ++ni)
      #pragma unroll
      for (int r = 0; r < 4; ++r)
        out[(size_t)(crow + mi*16 + r) * N + ccol + ni*16] = (TO)acc[mi][ni][r];
}

// ---------------------------------------------------------------------------
// MFMA flash attention (r9/r11 structure, passing at 46.5us).
// ---------------------------------------------------------------------------
__global__ __launch_bounds__(512, 4) void k_attn16(const half_t* __restrict__ qkv,
                                                   half_t* __restrict__ y16) {
  __shared__ __align__(16) half_t Ks[2][64*72];
  __shared__ __align__(16) half_t Vt[2][64*72];   // XOR-swizzled [dim][key-pair]
  __shared__ __align__(16) half_t Ps[8][16*72];
  const int tid = threadIdx.x;
  const int wave = tid >> 6, lane = tid & 63;
  const int l15 = lane & 15, lg = lane >> 4;
  const int w4 = wave & 3;
  const int bh = blockIdx.x, b = bh >> 4, h = bh & 15;
  const int j = blockIdx.y;
  const int qtB = 31 - j;
  const int qt = (wave >> 2) ? qtB : j;    // this wave's q-tile

  const size_t row = (size_t)(b * TT + qt * 64 + w4 * 16 + l15);
  const half_t* qp = qkv + row * C3 + h * HD + lg * 8;
  const half8 q0 = *reinterpret_cast<const half8*>(qp)      * (half_t)0.125f;
  const half8 q1 = *reinterpret_cast<const half8*>(qp + 32) * (half_t)0.125f;

  float m = -3.0e38f;
  f32x4 yacc[4];
  f32x4 lacc = f32x4{0,0,0,0};
  #pragma unroll
  for (int n = 0; n < 4; ++n) yacc[n] = f32x4{0,0,0,0};

  const int sj = tid >> 3, sc = (tid & 7) * 8;
  const int vkp = tid >> 4, vd0 = (tid & 15) * 4;
  const int vxor = ((vd0 >> 3) & 7) << 2;
  const int pxor = (l15 & 3) << 3;
  half_t* pw = &Ps[wave][0];

  int vdw0[4], vdw1[4];
  #pragma unroll
  for (int n = 0; n < 4; ++n) {
    const int d = n*16 + l15;
    const int x = ((n*2 + (l15 >> 3)) & 7) << 2;
    vdw0[n] = (d*36 + lg*4) ^ x;
    vdw1[n] = (d*36 + 16 + lg*4) ^ x;
  }

  half8 ones8;
  #pragma unroll
  for (int i = 0; i < 8; ++i) ones8[i] = (half_t)1.0f;

  half8 k0r; uint2 u0r, u1r;
  const half_t* kvb = qkv + ((size_t)b * TT) * C3 + CC + h * HD;
  auto kload = [&](int kt) {
    const half_t* kp = kvb + (size_t)(kt*64 + sj) * C3 + sc;
    k0r = *reinterpret_cast<const half8*>(kp);
    const half_t* vp = kvb + (size_t)(kt*64 + vkp*2) * C3 + CC + vd0;
    u0r = *reinterpret_cast<const uint2*>(vp);
    u1r = *reinterpret_cast<const uint2*>(vp + C3);
  };
  auto stage = [&](int buf) {
    *reinterpret_cast<half8*>(&Ks[buf][0] + sj*72 + sc) = k0r;
    uint32_t* vt32 = reinterpret_cast<uint32_t*>(&Vt[buf][0]);
    vt32[((vd0+0)*36 + vkp) ^ vxor] = __builtin_amdgcn_perm(u1r.x, u0r.x, 0x05040100u);
    vt32[((vd0+1)*36 + vkp) ^ vxor] = __builtin_amdgcn_perm(u1r.x, u0r.x, 0x07060302u);
    vt32[((vd0+2)*36 + vkp) ^ vxor] = __builtin_amdgcn_perm(u1r.y, u0r.y, 0x05040100u);
    vt32[((vd0+3)*36 + vkp) ^ vxor] = __builtin_amdgcn_perm(u1r.y, u0r.y, 0x07060302u);
  };

  kload(0);
  stage(0);
  kload(1);
  __syncthreads();
  for (int kt = 0; kt <= qtB; ++kt) {
    const int cur = kt & 1;
    if (kt < qtB) {
      stage(cur ^ 1);
      if (kt + 2 <= qtB) kload(kt + 2);
    }
    if (kt <= qt) {
      const half_t* ksb = &Ks[cur][0];
      const uint32_t* vt32 = reinterpret_cast<const uint32_t*>(&Vt[cur][0]);
      f32x4 sacc[4];
      __builtin_amdgcn_s_setprio(1);
      #pragma unroll
      for (int kg = 0; kg < 4; ++kg) {
        const half8 a0 = *reinterpret_cast<const half8*>(ksb + (kg*16 + l15)*72 + lg*8);
        const half8 a1 = *reinterpret_cast<const half8*>(ksb + (kg*16 + l15)*72 + lg*8 + 32);
        f32x4 t = f32x4{0,0,0,0};
        t = __builtin_amdgcn_mfma_f32_16x16x32_f16(a0, q0, t, 0, 0, 0);
        t = __builtin_amdgcn_mfma_f32_16x16x32_f16(a1, q1, t, 0, 0, 0);
        sacc[kg] = t;
      }
      __builtin_amdgcn_s_setprio(0);
      float sv[16]; float tm = -3.0e38f;
      const bool diag = (kt == qt);
      #pragma unroll
      for (int kg = 0; kg < 4; ++kg)
        #pragma unroll
        for (int r = 0; r < 4; ++r) {
          float s = sacc[kg][r];
          if (diag && (kg*16 + lg*4 + r > w4*16 + l15)) s = -1e30f;
          sv[kg*4 + r] = s;
          tm = fmaxf(tm, s);
        }
      tm = fmaxf(tm, __shfl_xor(tm, 16));
      tm = fmaxf(tm, __shfl_xor(tm, 32));
      if (!__all(tm <= m + DEFER_THR)) {
        const float mn = fmaxf(m, tm);
        const float alpha = __builtin_amdgcn_exp2f((m - mn) * LOG2E);
        #pragma unroll
        for (int n = 0; n < 4; ++n) yacc[n] *= alpha;
        lacc *= alpha;
        m = mn;
      }
      const float nm = -m * LOG2E;
      #pragma unroll
      for (int i = 0; i < 16; ++i)
        sv[i] = __builtin_amdgcn_exp2f(fmaf(sv[i], LOG2E, nm));
      uint32_t* prow = reinterpret_cast<uint32_t*>(pw) + l15*36;
      #pragma unroll
      for (int kg = 0; kg < 4; ++kg) {
        uint2 pr;
        pr.x = pk_h2(sv[kg*4 + 0], sv[kg*4 + 1]);
        pr.y = pk_h2(sv[kg*4 + 2], sv[kg*4 + 3]);
        *reinterpret_cast<uint2*>(prow + ((kg*8 + lg*2) ^ pxor)) = pr;
      }
      __builtin_amdgcn_sched_barrier(0);
      const half8 pb0 = *reinterpret_cast<const half8*>(
          pw + (l15*36 + ((lg*4) ^ pxor)) * 2);
      const half8 pb1 = *reinterpret_cast<const half8*>(
          pw + (l15*36 + ((16 + lg*4) ^ pxor)) * 2);
      __builtin_amdgcn_s_setprio(1);
      #pragma unroll
      for (int n = 0; n < 4; ++n) {
        const half8 va0 = *reinterpret_cast<const half8*>(vt32 + vdw0[n]);
        const half8 va1 = *reinterpret_cast<const half8*>(vt32 + vdw1[n]);
        yacc[n] = __builtin_amdgcn_mfma_f32_16x16x32_f16(va0, pb0, yacc[n], 0, 0, 0);
        yacc[n] = __builtin_amdgcn_mfma_f32_16x16x32_f16(va1, pb1, yacc[n], 0, 0, 0);
      }
      lacc = __builtin_amdgcn_mfma_f32_16x16x32_f16(ones8, pb0, lacc, 0, 0, 0);
      lacc = __builtin_amdgcn_mfma_f32_16x16x32_f16(ones8, pb1, lacc, 0, 0, 0);
      __builtin_amdgcn_s_setprio(0);
    }
    __syncthreads();
  }

  const float inv = 1.0f / lacc[0];
  float v[16];
  #pragma unroll
  for (int n = 0; n < 4; ++n)
    #pragma unroll
    for (int r = 0; r < 4; ++r) v[n*4 + r] = yacc[n][r] * inv;
  half_t* yp = y16 + row * CC + h * HD;
  #pragma unroll
  for (int g = 0; g < 2; ++g) {
    float am = 0.f;
    #pragma unroll
    for (int t = 0; t < 8; ++t) am = fmaxf(am, fabsf(v[g*8 + t]));
    am = fmaxf(am, __shfl_xor(am, 16));
    am = fmaxf(am, __shfl_xor(am, 32));
    const float s = fmaxf(am / 127.0f, 1e-8f);
    const float qi = 1.0f / s;
    #pragma unroll
    for (int nn = 0; nn < 2; ++nn) {
      const int n = g*2 + nn;
      union { half_t h4[4]; uint64_t u; } pk;
      #pragma unroll
      for (int r = 0; r < 4; ++r) {
        float q = fminf(fmaxf(rintf(v[n*4 + r] * qi), -127.f), 127.f);
        pk.h4[r] = (half_t)(q * s);
      }
      *reinterpret_cast<uint64_t*>(yp + n*16 + lg*4) = pk.u;
    }
  }
}

// ---------------------------------------------------------------------------
// residual (x + proj_part0 + proj_part1) + stats + output quantization.
// ---------------------------------------------------------------------------
__global__ __launch_bounds__(256) void k_final(
    const float* __restrict__ x, const half_t* __restrict__ p0,
    const half_t* __restrict__ p1,
    float* __restrict__ out_fpx, float* __restrict__ out_qo, float* __restrict__ out_so,
    float* __restrict__ out_mean, float* __restrict__ out_rstd) {
  __shared__ float red[16];
  int row = blockIdx.x;
  int tid = threadIdx.x;
  size_t base = (size_t)row * CC + tid * 4;
  float4 xv = *reinterpret_cast<const float4*>(x + base);
  union { uint64_t u; half_t h[4]; } pa, pb;
  pa.u = *reinterpret_cast<const uint64_t*>(p0 + base);
  pb.u = *reinterpret_cast<const uint64_t*>(p1 + base);
  float4 f;
  f.x = xv.x + (float)pa.h[0] + (float)pb.h[0];
  f.y = xv.y + (float)pa.h[1] + (float)pb.h[1];
  f.z = xv.z + (float)pa.h[2] + (float)pb.h[2];
  f.w = xv.w + (float)pa.h[3] + (float)pb.h[3];
  *reinterpret_cast<float4*>(out_fpx + base) = f;
  float sum = f.x + f.y + f.z + f.w;
  float sq  = f.x*f.x + f.y*f.y + f.z*f.z + f.w*f.w;
  #pragma unroll
  for (int off = 1; off < 64; off <<= 1) {
    sum += __shfl_xor(sum, off);
    sq  += __shfl_xor(sq, off);
  }
  int wid = tid >> 6, lane = tid & 63;
  if (lane == 0) { red[wid] = sum; red[8 + wid] = sq; }
  __syncthreads();
  if (tid == 0) {
    float s4 = red[0] + red[1] + red[2] + red[3];
    float q4 = red[8] + red[9] + red[10] + red[11];
    float mu = s4 * (1.0f / CC);
    float var = q4 * (1.0f / CC) - mu * mu;
    out_mean[row] = mu;
    out_rstd[row] = 1.0f / sqrtf(var + 1e-5f);
  }
  float amax = fmaxf(fmaxf(fabsf(f.x), fabsf(f.y)), fmaxf(fabsf(f.z), fabsf(f.w)));
  #pragma unroll
  for (int off = 1; off < 8; off <<= 1) amax = fmaxf(amax, __shfl_xor(amax, off, 8));
  float s = fmaxf(amax / 127.0f, 1e-8f);
  int g = tid >> 3, li = tid & 7;
  if (li == 0) out_so[row * NG + g] = s;
  float4 qo;
  qo.x = fminf(fmaxf(rintf(f.x / s), -127.f), 127.f);
  qo.y = fminf(fmaxf(rintf(f.y / s), -127.f), 127.f);
  qo.z = fminf(fmaxf(rintf(f.z / s), -127.f), 127.f);
  qo.w = fminf(fmaxf(rintf(f.w / s), -127.f), 127.f);
  *reinterpret_cast<float4*>(out_qo + base) = qo;
}

// ---------------------------------------------------------------------------
extern "C" void kernel_launch(void* const* d_in, const int* in_sizes, int n_in,
                              void* d_out, int out_size, void* d_ws, size_t ws_size,
                              hipStream_t stream) {
  const float* x    = (const float*)d_in[0];
  const int*   qx   = (const int*)d_in[1];
  const float* sx   = (const float*)d_in[2];
  const float* mean = (const float*)d_in[3];
  const float* rstd = (const float*)d_in[4];
  const float* lnw  = (const float*)d_in[5];
  const float* w1   = (const float*)d_in[6];
  const float* w2   = (const float*)d_in[7];

  float* out = (float*)d_out;
  float* o_fpx  = out;
  float* o_qo   = o_fpx + (size_t)ROWS * CC;
  float* o_so   = o_qo  + (size_t)ROWS * CC;
  float* o_mean = o_so  + (size_t)ROWS * NG;
  float* o_rstd = o_mean + ROWS;

  size_t off = 0;
  char* wsb = (char*)d_ws;
  auto alloc = [&](size_t bytes) -> void* {
    void* p = wsb + off;
    off += (bytes + 255) & ~(size_t)255;
    return p;
  };
  half_t* h16   = (half_t*)alloc((size_t)ROWS * CC * 2);
  half_t* w116  = (half_t*)alloc((size_t)C3 * CC * 2);
  half_t* w216  = (half_t*)alloc((size_t)CC * CC * 2);
  half_t* qkv16 = (half_t*)alloc((size_t)ROWS * C3 * 2);
  half_t* y16   = (half_t*)alloc((size_t)ROWS * CC * 2);
  half_t* proj  = (half_t*)alloc((size_t)2 * ROWS * CC * 2);   // 2 K-slices

  // 1. merged pre-pass: weight fake-quant + LN/activation fake-quant
  k_pre<<<1024, 256, 0, stream>>>(w1, w2, w116, w216, qx, sx, mean, rstd, lnw, h16);
  // 2. qkv = h @ w1^T  (8-phase 256x256 pipelined MFMA GEMM)
  k_gemm8p<<<dim3(12, 16), 512, 0, stream>>>(h16, w116, qkv16);
  // 3. causal SDPA (r9 kernel: dbuf K/V, concurrent paired q-tiles)
  k_attn16<<<dim3(BB * NH, 16), 512, 0, stream>>>(qkv16, y16);
  // 4. proj = y @ w2^T  (fp16 MFMA, dbuf 2-phase, split-K=2)
  k_gemm16<half_t><<<dim3(CC / 128, ROWS / 128, 2), 256, 0, stream>>>(
      y16, w216, proj, CC, CC / 128, (CC / 128) * (ROWS / 128) / 8, 512);
  // 5. residual (x + p0 + p1) + stats + output quant
  k_final<<<ROWS, 256, 0, stream>>>(x, proj, proj + (size_t)ROWS * CC,
                                    o_fpx, o_qo, o_so, o_mean, o_rstd);
}

// Round 18
// 123.562 us; speedup vs baseline: 1.0308x; 1.0308x over previous
//
#include <hip/hip_runtime.h>
#include <stdint.h>

// Problem constants
#define BB 2
#define TT 2048
#define CC 1024
#define NH 16
#define HD 64
#define NG 32              // groups per C row (group size 32)
#define ROWS (BB*TT)       // 4096
#define C3 (3*CC)          // 3072

typedef _Float16 half_t;
typedef __attribute__((ext_vector_type(8))) _Float16 half8;
typedef __attribute__((ext_vector_type(2))) __fp16 fp16x2;
typedef __attribute__((ext_vector_type(4))) float f32x4;

#define GLDS16(g, l) __builtin_amdgcn_global_load_lds( \
    (__attribute__((address_space(1))) void*)(g), \
    (__attribute__((address_space(3))) void*)(l), 16, 0, 0)

#define LOG2E 1.44269504f
#define DEFER_THR 5.5451774f   /* 8 / log2(e) */

__device__ __forceinline__ uint32_t pk_h2(float a, float b) {
  union { fp16x2 h; uint32_t u; } cv;
  cv.h = __builtin_amdgcn_cvt_pkrtz(a, b);
  return cv.u;
}

// ---------------------------------------------------------------------------
// merged pre-pass: blocks [0,512) = weight fake-quant (w1|w2 -> fp16 qdq);
// blocks [512,1024) = dequant(qx)+LN+fake-quant -> fp16 h.
// ---------------------------------------------------------------------------
__global__ void k_pre(const float* __restrict__ w1, const float* __restrict__ w2,
                      half_t* __restrict__ o1, half_t* __restrict__ o2,
                      const int* __restrict__ qx, const float* __restrict__ sx,
                      const float* __restrict__ mean, const float* __restrict__ rstd,
                      const float* __restrict__ lnw, half_t* __restrict__ h16) {
  const int blk = blockIdx.x;
  if (blk < 512) {
    // ---- weight fake-quant ----
    int g = blk * blockDim.x + threadIdx.x;
    const float* src; half_t* dst; int gl;
    if (g < C3 * NG) { src = w1; dst = o1; gl = g; }
    else             { src = w2; dst = o2; gl = g - C3 * NG; }
    const float4* p = reinterpret_cast<const float4*>(src + (size_t)gl * 32);
    float v[32]; float amax = 0.f;
    #pragma unroll
    for (int i = 0; i < 8; ++i) {
      float4 t = p[i];
      v[4*i] = t.x; v[4*i+1] = t.y; v[4*i+2] = t.z; v[4*i+3] = t.w;
      amax = fmaxf(amax, fmaxf(fmaxf(fabsf(t.x), fabsf(t.y)), fmaxf(fabsf(t.z), fabsf(t.w))));
    }
    float s = fmaxf(amax / 127.0f, 1e-8f);
    half_t* o = dst + (size_t)gl * 32;
    #pragma unroll
    for (int c = 0; c < 4; ++c) {
      half8 ov;
      #pragma unroll
      for (int jj = 0; jj < 8; ++jj) {
        float q = fminf(fmaxf(rintf(v[c*8+jj] / s), -127.f), 127.f);
        ov[jj] = (half_t)(q * s);
      }
      *reinterpret_cast<half8*>(o + c*8) = ov;
    }
  } else {
    // ---- LN + activation fake-quant ----
    int g = (blk - 512) * blockDim.x + threadIdx.x;
    int row = g >> 5, grp = g & 31;
    float sxv = sx[g];
    float mu = mean[row], rs = rstd[row];
    const int4* qp = reinterpret_cast<const int4*>(qx + (size_t)row * CC + grp * 32);
    const float4* wp = reinterpret_cast<const float4*>(lnw + grp * 32);
    float v[32]; float amax = 0.f;
    #pragma unroll
    for (int i = 0; i < 8; ++i) {
      int4 qv = qp[i]; float4 wv = wp[i];
      float h0 = ((float)qv.x * sxv - mu) * rs * wv.x;
      float h1 = ((float)qv.y * sxv - mu) * rs * wv.y;
      float h2 = ((float)qv.z * sxv - mu) * rs * wv.z;
      float h3 = ((float)qv.w * sxv - mu) * rs * wv.w;
      v[4*i] = h0; v[4*i+1] = h1; v[4*i+2] = h2; v[4*i+3] = h3;
      amax = fmaxf(amax, fmaxf(fmaxf(fabsf(h0), fabsf(h1)), fmaxf(fabsf(h2), fabsf(h3))));
    }
    float s = fmaxf(amax / 127.0f, 1e-8f);
    half_t* o = h16 + (size_t)row * CC + grp * 32;
    #pragma unroll
    for (int c = 0; c < 4; ++c) {
      half8 ov;
      #pragma unroll
      for (int jj = 0; jj < 8; ++jj) {
        float q = fminf(fmaxf(rintf(v[c*8+jj] / s), -127.f), 127.f);
        ov[jj] = (half_t)(q * s);
      }
      *reinterpret_cast<half8*>(o + c*8) = ov;
    }
  }
}

// ---------------------------------------------------------------------------
// fp16 MFMA GEMM (r11/r16, passing): 128x128 tile, BK=32 double-buffered,
// XCD-bijective swizzle, split-K via blockIdx.z.
// ---------------------------------------------------------------------------
template<typename TO>
__global__ __launch_bounds__(256) void k_gemm16(const half_t* __restrict__ A,
                                                const half_t* __restrict__ B,
                                                TO* __restrict__ Out, int N,
                                                int gx, int cpx, int klen) {
  __shared__ __align__(16) half_t As[2][128*32];
  __shared__ __align__(16) half_t Bs[2][128*32];
  const int tid = threadIdx.x;
  const int wave = tid >> 6, lane = tid & 63;
  const int l15 = lane & 15, lg = lane >> 4;
  const int flat = blockIdx.y * gx + blockIdx.x;
  const int swz = (flat & 7) * cpx + (flat >> 3);
  const int m0 = (swz / gx) * 128, n0 = (swz % gx) * 128;
  const int kbeg = blockIdx.z * klen;
  TO* out = Out + (size_t)blockIdx.z * ROWS * N;
  const int wm = (wave >> 1) * 64, wn = (wave & 1) * 64;
  f32x4 acc[4][4];
  #pragma unroll
  for (int i = 0; i < 4; ++i)
    #pragma unroll
    for (int jj = 0; jj < 4; ++jj) acc[i][jj] = f32x4{0.f, 0.f, 0.f, 0.f};
  const int srow = lane >> 2;
  const int scol = (lane & 3) * 8;
  const int seg0 = wave * 2;
  auto stage = [&](int buf, int k0) {
    #pragma unroll
    for (int s = 0; s < 2; ++s) {
      const int seg = seg0 + s;
      GLDS16(A + (size_t)(m0 + seg*16 + srow) * 1024 + k0 + scol, &As[buf][0] + seg*512);
      GLDS16(B + (size_t)(n0 + seg*16 + srow) * 1024 + k0 + scol, &Bs[buf][0] + seg*512);
    }
  };
  stage(0, kbeg);
  __syncthreads();
  int cur = 0;
  for (int k0 = kbeg; k0 < kbeg + klen; k0 += 32) {
    if (k0 + 32 < kbeg + klen) stage(cur ^ 1, k0 + 32);
    half8 af[4], bf[4];
    #pragma unroll
    for (int i = 0; i < 4; ++i) {
      af[i] = *reinterpret_cast<const half8*>(&As[cur][0] + (wm + i*16 + l15)*32 + lg*8);
      bf[i] = *reinterpret_cast<const half8*>(&Bs[cur][0] + (wn + i*16 + l15)*32 + lg*8);
    }
    #pragma unroll
    for (int mi = 0; mi < 4; ++mi)
      #pragma unroll
      for (int ni = 0; ni < 4; ++ni)
        acc[mi][ni] = __builtin_amdgcn_mfma_f32_16x16x32_f16(af[mi], bf[ni], acc[mi][ni], 0, 0, 0);
    __syncthreads();
    cur ^= 1;
  }
  const int crow = m0 + wm + lg * 4;
  const int ccol = n0 + wn + l15;
  #pragma unroll
  for (int mi = 0; mi < 4; ++mi)
    #pragma unroll
    for (int ni = 0; ni < 4; ++ni)
      #pragma unroll
      for (int r = 0; r < 4; ++r)
        out[(size_t)(crow + mi*16 + r) * N + ccol + ni*16] = (TO)acc[mi][ni][r];
}

// ---------------------------------------------------------------------------
// MFMA flash attention (r9/r11/r16 structure, passing at 46.5us).
// Paired q-tiles {j, 31-j}, 512 threads / 8 waves: waves 0-3 tile A(=j),
// waves 4-7 tile B(=31-j) concurrently. Double-buffered K/V staging.
// ---------------------------------------------------------------------------
__global__ __launch_bounds__(512, 4) void k_attn16(const half_t* __restrict__ qkv,
                                                   half_t* __restrict__ y16) {
  __shared__ __align__(16) half_t Ks[2][64*72];
  __shared__ __align__(16) half_t Vt[2][64*72];   // XOR-swizzled [dim][key-pair]
  __shared__ __align__(16) half_t Ps[8][16*72];
  const int tid = threadIdx.x;
  const int wave = tid >> 6, lane = tid & 63;
  const int l15 = lane & 15, lg = lane >> 4;
  const int w4 = wave & 3;
  const int bh = blockIdx.x, b = bh >> 4, h = bh & 15;
  const int j = blockIdx.y;
  const int qtB = 31 - j;
  const int qt = (wave >> 2) ? qtB : j;    // this wave's q-tile

  // Q fragment, prescaled by 1/sqrt(hd)=0.125 (exact in fp16)
  const size_t row = (size_t)(b * TT + qt * 64 + w4 * 16 + l15);
  const half_t* qp = qkv + row * C3 + h * HD + lg * 8;
  const half8 q0 = *reinterpret_cast<const half8*>(qp)      * (half_t)0.125f;
  const half8 q1 = *reinterpret_cast<const half8*>(qp + 32) * (half_t)0.125f;

  float m = -3.0e38f;
  f32x4 yacc[4];
  f32x4 lacc = f32x4{0,0,0,0};
  #pragma unroll
  for (int n = 0; n < 4; ++n) yacc[n] = f32x4{0,0,0,0};

  // staging maps (512 threads)
  const int sj = tid >> 3, sc = (tid & 7) * 8;       // K: key sj, dims sc..sc+7
  const int vkp = tid >> 4, vd0 = (tid & 15) * 4;    // V: keys 2vkp,2vkp+1, dims vd0..+3
  const int vxor = ((vd0 >> 3) & 7) << 2;            // dword-index XOR (16B granular)
  const int pxor = (l15 & 3) << 3;                   // P dword-offset XOR
  half_t* pw = &Ps[wave][0];

  // precomputed V^T read dword offsets (relative to buffer base)
  int vdw0[4], vdw1[4];
  #pragma unroll
  for (int n = 0; n < 4; ++n) {
    const int d = n*16 + l15;
    const int x = ((n*2 + (l15 >> 3)) & 7) << 2;
    vdw0[n] = (d*36 + lg*4) ^ x;
    vdw1[n] = (d*36 + 16 + lg*4) ^ x;
  }

  half8 ones8;
  #pragma unroll
  for (int i = 0; i < 8; ++i) ones8[i] = (half_t)1.0f;

  // K/V prefetch registers
  half8 k0r; uint2 u0r, u1r;
  const half_t* kvb = qkv + ((size_t)b * TT) * C3 + CC + h * HD;
  auto kload = [&](int kt) {
    const half_t* kp = kvb + (size_t)(kt*64 + sj) * C3 + sc;
    k0r = *reinterpret_cast<const half8*>(kp);
    const half_t* vp = kvb + (size_t)(kt*64 + vkp*2) * C3 + CC + vd0;
    u0r = *reinterpret_cast<const uint2*>(vp);
    u1r = *reinterpret_cast<const uint2*>(vp + C3);
  };
  auto stage = [&](int buf) {
    *reinterpret_cast<half8*>(&Ks[buf][0] + sj*72 + sc) = k0r;
    uint32_t* vt32 = reinterpret_cast<uint32_t*>(&Vt[buf][0]);
    vt32[((vd0+0)*36 + vkp) ^ vxor] = __builtin_amdgcn_perm(u1r.x, u0r.x, 0x05040100u);
    vt32[((vd0+1)*36 + vkp) ^ vxor] = __builtin_amdgcn_perm(u1r.x, u0r.x, 0x07060302u);
    vt32[((vd0+2)*36 + vkp) ^ vxor] = __builtin_amdgcn_perm(u1r.y, u0r.y, 0x05040100u);
    vt32[((vd0+3)*36 + vkp) ^ vxor] = __builtin_amdgcn_perm(u1r.y, u0r.y, 0x07060302u);
  };

  kload(0);
  stage(0);
  kload(1);                     // qtB >= 16 always, safe
  __syncthreads();
  for (int kt = 0; kt <= qtB; ++kt) {
    const int cur = kt & 1;
    if (kt < qtB) {
      stage(cur ^ 1);           // write OTHER buffer: overlaps compute of cur
      if (kt + 2 <= qtB) kload(kt + 2);
    }
    if (kt <= qt) {
      const half_t* ksb = &Ks[cur][0];
      const uint32_t* vt32 = reinterpret_cast<const uint32_t*>(&Vt[cur][0]);
      // ---- QK^T ----
      f32x4 sacc[4];
      __builtin_amdgcn_s_setprio(1);
      #pragma unroll
      for (int kg = 0; kg < 4; ++kg) {
        const half8 a0 = *reinterpret_cast<const half8*>(ksb + (kg*16 + l15)*72 + lg*8);
        const half8 a1 = *reinterpret_cast<const half8*>(ksb + (kg*16 + l15)*72 + lg*8 + 32);
        f32x4 t = f32x4{0,0,0,0};
        t = __builtin_amdgcn_mfma_f32_16x16x32_f16(a0, q0, t, 0, 0, 0);
        t = __builtin_amdgcn_mfma_f32_16x16x32_f16(a1, q1, t, 0, 0, 0);
        sacc[kg] = t;
      }
      __builtin_amdgcn_s_setprio(0);
      // ---- softmax ----
      float sv[16]; float tm = -3.0e38f;
      const bool diag = (kt == qt);
      #pragma unroll
      for (int kg = 0; kg < 4; ++kg)
        #pragma unroll
        for (int r = 0; r < 4; ++r) {
          float s = sacc[kg][r];
          if (diag && (kg*16 + lg*4 + r > w4*16 + l15)) s = -1e30f;
          sv[kg*4 + r] = s;
          tm = fmaxf(tm, s);
        }
      tm = fmaxf(tm, __shfl_xor(tm, 16));
      tm = fmaxf(tm, __shfl_xor(tm, 32));
      if (!__all(tm <= m + DEFER_THR)) {
        const float mn = fmaxf(m, tm);
        const float alpha = __builtin_amdgcn_exp2f((m - mn) * LOG2E);
        #pragma unroll
        for (int n = 0; n < 4; ++n) yacc[n] *= alpha;
        lacc *= alpha;
        m = mn;
      }
      const float nm = -m * LOG2E;
      #pragma unroll
      for (int i = 0; i < 16; ++i)
        sv[i] = __builtin_amdgcn_exp2f(fmaf(sv[i], LOG2E, nm));
      // P -> wave-private LDS, XOR-swizzled (full-bank spread)
      uint32_t* prow = reinterpret_cast<uint32_t*>(pw) + l15*36;
      #pragma unroll
      for (int kg = 0; kg < 4; ++kg) {
        uint2 pr;
        pr.x = pk_h2(sv[kg*4 + 0], sv[kg*4 + 1]);
        pr.y = pk_h2(sv[kg*4 + 2], sv[kg*4 + 3]);
        *reinterpret_cast<uint2*>(prow + ((kg*8 + lg*2) ^ pxor)) = pr;
      }
      __builtin_amdgcn_sched_barrier(0);
      const half8 pb0 = *reinterpret_cast<const half8*>(
          pw + (l15*36 + ((lg*4) ^ pxor)) * 2);
      const half8 pb1 = *reinterpret_cast<const half8*>(
          pw + (l15*36 + ((16 + lg*4) ^ pxor)) * 2);
      // ---- PV + row-sum ----
      __builtin_amdgcn_s_setprio(1);
      #pragma unroll
      for (int n = 0; n < 4; ++n) {
        const half8 va0 = *reinterpret_cast<const half8*>(vt32 + vdw0[n]);
        const half8 va1 = *reinterpret_cast<const half8*>(vt32 + vdw1[n]);
        yacc[n] = __builtin_amdgcn_mfma_f32_16x16x32_f16(va0, pb0, yacc[n], 0, 0, 0);
        yacc[n] = __builtin_amdgcn_mfma_f32_16x16x32_f16(va1, pb1, yacc[n], 0, 0, 0);
      }
      lacc = __builtin_amdgcn_mfma_f32_16x16x32_f16(ones8, pb0, lacc, 0, 0, 0);
      lacc = __builtin_amdgcn_mfma_f32_16x16x32_f16(ones8, pb1, lacc, 0, 0, 0);
      __builtin_amdgcn_s_setprio(0);
    }
    __syncthreads();
  }

  // epilogue: normalize + fused group-32 fake-quant, write fp16 qdq values
  const float inv = 1.0f / lacc[0];
  float v[16];
  #pragma unroll
  for (int n = 0; n < 4; ++n)
    #pragma unroll
    for (int r = 0; r < 4; ++r) v[n*4 + r] = yacc[n][r] * inv;
  half_t* yp = y16 + row * CC + h * HD;
  #pragma unroll
  for (int g = 0; g < 2; ++g) {
    float am = 0.f;
    #pragma unroll
    for (int t = 0; t < 8; ++t) am = fmaxf(am, fabsf(v[g*8 + t]));
    am = fmaxf(am, __shfl_xor(am, 16));
    am = fmaxf(am, __shfl_xor(am, 32));
    const float s = fmaxf(am / 127.0f, 1e-8f);
    const float qi = 1.0f / s;
    #pragma unroll
    for (int nn = 0; nn < 2; ++nn) {
      const int n = g*2 + nn;
      union { half_t h4[4]; uint64_t u; } pk;
      #pragma unroll
      for (int r = 0; r < 4; ++r) {
        float q = fminf(fmaxf(rintf(v[n*4 + r] * qi), -127.f), 127.f);
        pk.h4[r] = (half_t)(q * s);
      }
      *reinterpret_cast<uint64_t*>(yp + n*16 + lg*4) = pk.u;
    }
  }
}

// ---------------------------------------------------------------------------
// residual (x + proj_part0 + proj_part1) + stats + output quantization.
// ---------------------------------------------------------------------------
__global__ __launch_bounds__(256) void k_final(
    const float* __restrict__ x, const half_t* __restrict__ p0,
    const half_t* __restrict__ p1,
    float* __restrict__ out_fpx, float* __restrict__ out_qo, float* __restrict__ out_so,
    float* __restrict__ out_mean, float* __restrict__ out_rstd) {
  __shared__ float red[16];
  int row = blockIdx.x;
  int tid = threadIdx.x;
  size_t base = (size_t)row * CC + tid * 4;
  float4 xv = *reinterpret_cast<const float4*>(x + base);
  union { uint64_t u; half_t h[4]; } pa, pb;
  pa.u = *reinterpret_cast<const uint64_t*>(p0 + base);
  pb.u = *reinterpret_cast<const uint64_t*>(p1 + base);
  float4 f;
  f.x = xv.x + (float)pa.h[0] + (float)pb.h[0];
  f.y = xv.y + (float)pa.h[1] + (float)pb.h[1];
  f.z = xv.z + (float)pa.h[2] + (float)pb.h[2];
  f.w = xv.w + (float)pa.h[3] + (float)pb.h[3];
  *reinterpret_cast<float4*>(out_fpx + base) = f;
  float sum = f.x + f.y + f.z + f.w;
  float sq  = f.x*f.x + f.y*f.y + f.z*f.z + f.w*f.w;
  #pragma unroll
  for (int off = 1; off < 64; off <<= 1) {
    sum += __shfl_xor(sum, off);
    sq  += __shfl_xor(sq, off);
  }
  int wid = tid >> 6, lane = tid & 63;
  if (lane == 0) { red[wid] = sum; red[8 + wid] = sq; }
  __syncthreads();
  if (tid == 0) {
    float s4 = red[0] + red[1] + red[2] + red[3];
    float q4 = red[8] + red[9] + red[10] + red[11];
    float mu = s4 * (1.0f / CC);
    float var = q4 * (1.0f / CC) - mu * mu;
    out_mean[row] = mu;
    out_rstd[row] = 1.0f / sqrtf(var + 1e-5f);
  }
  float amax = fmaxf(fmaxf(fabsf(f.x), fabsf(f.y)), fmaxf(fabsf(f.z), fabsf(f.w)));
  #pragma unroll
  for (int off = 1; off < 8; off <<= 1) amax = fmaxf(amax, __shfl_xor(amax, off, 8));
  float s = fmaxf(amax / 127.0f, 1e-8f);
  int g = tid >> 3, li = tid & 7;
  if (li == 0) out_so[row * NG + g] = s;
  float4 qo;
  qo.x = fminf(fmaxf(rintf(f.x / s), -127.f), 127.f);
  qo.y = fminf(fmaxf(rintf(f.y / s), -127.f), 127.f);
  qo.z = fminf(fmaxf(rintf(f.z / s), -127.f), 127.f);
  qo.w = fminf(fmaxf(rintf(f.w / s), -127.f), 127.f);
  *reinterpret_cast<float4*>(out_qo + base) = qo;
}

// ---------------------------------------------------------------------------
extern "C" void kernel_launch(void* const* d_in, const int* in_sizes, int n_in,
                              void* d_out, int out_size, void* d_ws, size_t ws_size,
                              hipStream_t stream) {
  const float* x    = (const float*)d_in[0];
  const int*   qx   = (const int*)d_in[1];
  const float* sx   = (const float*)d_in[2];
  const float* mean = (const float*)d_in[3];
  const float* rstd = (const float*)d_in[4];
  const float* lnw  = (const float*)d_in[5];
  const float* w1   = (const float*)d_in[6];
  const float* w2   = (const float*)d_in[7];

  float* out = (float*)d_out;
  float* o_fpx  = out;
  float* o_qo   = o_fpx + (size_t)ROWS * CC;
  float* o_so   = o_qo  + (size_t)ROWS * CC;
  float* o_mean = o_so  + (size_t)ROWS * NG;
  float* o_rstd = o_mean + ROWS;

  size_t off = 0;
  char* wsb = (char*)d_ws;
  auto alloc = [&](size_t bytes) -> void* {
    void* p = wsb + off;
    off += (bytes + 255) & ~(size_t)255;
    return p;
  };
  half_t* h16   = (half_t*)alloc((size_t)ROWS * CC * 2);
  half_t* w116  = (half_t*)alloc((size_t)C3 * CC * 2);
  half_t* w216  = (half_t*)alloc((size_t)CC * CC * 2);
  half_t* qkv16 = (half_t*)alloc((size_t)ROWS * C3 * 2);
  half_t* y16   = (half_t*)alloc((size_t)ROWS * CC * 2);
  half_t* proj  = (half_t*)alloc((size_t)2 * ROWS * CC * 2);   // 2 K-slices

  // 1. merged pre-pass: weight fake-quant + LN/activation fake-quant
  k_pre<<<1024, 256, 0, stream>>>(w1, w2, w116, w216, qx, sx, mean, rstd, lnw, h16);
  // 2. qkv = h @ w1^T  (fp16 MFMA, dbuf 2-phase, XCD-swizzled)
  k_gemm16<half_t><<<dim3(C3 / 128, ROWS / 128, 1), 256, 0, stream>>>(
      h16, w116, qkv16, C3, C3 / 128, (C3 / 128) * (ROWS / 128) / 8, 1024);
  // 3. causal SDPA (r9 kernel: dbuf K/V, concurrent paired q-tiles)
  k_attn16<<<dim3(BB * NH, 16), 512, 0, stream>>>(qkv16, y16);
  // 4. proj = y @ w2^T  (fp16 MFMA, dbuf 2-phase, split-K=2)
  k_gemm16<half_t><<<dim3(CC / 128, ROWS / 128, 2), 256, 0, stream>>>(
      y16, w216, proj, CC, CC / 128, (CC / 128) * (ROWS / 128) / 8, 512);
  // 5. residual (x + p0 + p1) + stats + output quant
  k_final<<<ROWS, 256, 0, stream>>>(x, proj, proj + (size_t)ROWS * CC,
                                    o_fpx, o_qo, o_so, o_mean, o_rstd);
}